// Round 4
// baseline (6584.084 us; speedup 1.0000x reference)
//
#include <hip/hip_runtime.h>
#include <hip/hip_fp16.h>

// ---------------------------------------------------------------------------
// 4-layer GRU stack (Keras reset_after), B=128, T=384, U=D=256.
// 256 persistent blocks = 4 layers x 8 chunks(16 rows) x 8 unit-slices(32 u).
// Weights LDS-resident (96 KB/block). Per step: M=16,N=96,K=512 fp16 MFMA.
// h exchanged through a 16-deep ring in ws with the DOCUMENTED system-scope
// release/acquire pattern: plain data stores -> fence(release,system) ->
// relaxed flag RMW; consumer polls flag -> fence(acquire,system) -> plain
// data loads. No reliance on posted-write ordering vs atomic RMWs.
// ---------------------------------------------------------------------------

#define LAYERS 4
#define TSTEPS 384
#define NCH    8
#define AP2    520                 // A row pitch (512 + 8 pad) in fp16 elems
#define WPL    (48 * 16 * 64 * 8)  // repacked weight elems per layer
#define TILE_STRIDE (16 * 64 * 8)  // 8192 elems per 16-col tile
#define RING   16

typedef _Float16 half8 __attribute__((ext_vector_type(8)));
typedef float    f32x4 __attribute__((ext_vector_type(4)));
typedef unsigned long long ull;

// ws layout (bytes)
#define WP_OFF   0
#define BP_OFF   (LAYERS * WPL * 2)                 // 3,145,728
#define FLAG_OFF (BP_OFF + LAYERS * 1024 * 4)       // +16 KB
#define FLAG_BYTES (LAYERS * NCH * TSTEPS * 4)      // 49,152
#define HBUF_OFF (4 * 1024 * 1024)
// hbuf: [l][c][slot(16)][row(16)][256] fp16 = 4 MB total

// ---------------------------------------------------------------------------
// Repack: W[l] -> [tile=48][kt=16][lane=64][8] fp16 B-fragments.
// n = tile*16 + (lane&15), k = kt*32 + (lane>>4)*8 + j; k<256 input kernel,
// k>=256 recurrent. Bias: [0:512]=b_in+b_rec (z,r), [512:768]=b_in_h,
// [768:1024]=b_rec_h.
// ---------------------------------------------------------------------------
__global__ void repack_kernel(const float* __restrict__ k0, const float* __restrict__ rk0,
                              const float* __restrict__ b0, const float* __restrict__ kern,
                              const float* __restrict__ rkern, const float* __restrict__ bias,
                              _Float16* __restrict__ Wp, float* __restrict__ Bp)
{
    int idx = blockIdx.x * 256 + threadIdx.x;
    const int total_w = LAYERS * WPL;
    if (idx < total_w) {
        int l = idx / WPL;
        int r = idx - l * WPL;
        int j    = r & 7;
        int lane = (r >> 3) & 63;
        int kt   = (r >> 9) & 15;
        int tile = r >> 13;
        int n = tile * 16 + (lane & 15);
        int k = kt * 32 + (lane >> 4) * 8 + j;
        float v;
        if (l == 0) {
            v = (k < 256) ? k0[(size_t)k * 768 + n] : rk0[(size_t)(k - 256) * 768 + n];
        } else {
            const float* kk = kern  + (size_t)(l - 1) * 256 * 768;
            const float* rk = rkern + (size_t)(l - 1) * 256 * 768;
            v = (k < 256) ? kk[(size_t)k * 768 + n] : rk[(size_t)(k - 256) * 768 + n];
        }
        Wp[idx] = (_Float16)v;
    } else {
        int ib = idx - total_w;
        if (ib < LAYERS * 1024) {
            int l = ib >> 10;
            int i = ib & 1023;
            const float* bs = (l == 0) ? b0 : (bias + (size_t)(l - 1) * 2 * 768);
            float v;
            if (i < 512)      v = bs[i] + bs[768 + i];
            else if (i < 768) v = bs[512 + (i - 512)];
            else              v = bs[768 + 512 + (i - 768)];
            Bp[l * 1024 + i] = v;
        }
    }
}

// ---------------------------------------------------------------------------
// Persistent GRU kernel: 384 threads = 6 waves; wave w computes one 16-col
// tile (z0 z1 r0 r1 h0 h1); waves 4,5 keep split accumulators (k<256 / k>=256).
// ---------------------------------------------------------------------------
__launch_bounds__(384, 1)
__global__ void gru_kernel(const float* __restrict__ x,
                           const _Float16* __restrict__ Wp,
                           const float* __restrict__ Bp,
                           _Float16* __restrict__ hbuf,
                           unsigned int* __restrict__ flags,
                           float* __restrict__ out)
{
    __shared__ _Float16 Wlds[6 * 16 * 64 * 8];   // 96 KB
    __shared__ _Float16 Ash[16 * AP2];           // 16.6 KB
    __shared__ float    Sc[8][16][17];           // 8.7 KB

    const int tid  = threadIdx.x;
    const int lane = tid & 63;
    const int w    = tid >> 6;
    const int lo16 = lane & 15;
    const int q    = lane >> 4;

    const int s = blockIdx.x & 7;          // unit slice
    const int c = (blockIdx.x >> 3) & 7;   // batch chunk
    const int l = blockIdx.x >> 6;         // layer
    const int b0row = c * 16;

    // ---- load this block's 6 weight tiles into LDS (once) ----
    {
        const int tiles[6] = {2*s, 2*s+1, 16+2*s, 17+2*s, 32+2*s, 33+2*s};
        const _Float16* wb = Wp + (size_t)l * WPL;
#pragma unroll
        for (int i = 0; i < 16; ++i) {
            int idx = tid + i * 384;         // half8 index 0..6143
            int tl  = idx >> 10;             // tile slot (1024 half8 per tile)
            int rem = idx & 1023;
            half8 v = *(const half8*)(wb + (size_t)tiles[tl] * TILE_STRIDE + rem * 8);
            *(half8*)(Wlds + (size_t)idx * 8) = v;
        }
    }

    // ---- per-gate-thread constants (tid<256: row=tid>>4, units gup,gup+1) ----
    const int grow = tid >> 4;
    const int gup  = (tid & 15) * 2;
    float bz[2] = {0,0}, br[2] = {0,0}, bi[2] = {0,0}, bh[2] = {0,0};
    float hprev[2] = {0.f, 0.f};
    if (tid < 256) {
        const float* bp = Bp + l * 1024;
        int ug = s * 32 + gup;
        bz[0] = bp[ug];       bz[1] = bp[ug + 1];
        br[0] = bp[256 + ug]; br[1] = bp[256 + ug + 1];
        bi[0] = bp[512 + ug]; bi[1] = bp[512 + ug + 1];
        bh[0] = bp[768 + ug]; bh[1] = bp[768 + ug + 1];
    }
    __syncthreads();

    unsigned int* fl_own = flags + (l * NCH + c) * TSTEPS;
    unsigned int* fl_up  = flags + ((l > 0 ? l - 1 : 0) * NCH + c) * TSTEPS;
    unsigned int* fl_dn  = flags + ((l < 3 ? l + 1 : 0) * NCH + c) * TSTEPS;

    _Float16*       hb_own = hbuf + (size_t)(l * NCH + c) * RING * 16 * 256;
    const _Float16* hb_up  = hbuf + (size_t)((l > 0 ? l - 1 : 0) * NCH + c) * RING * 16 * 256;

    auto wait8 = [&](unsigned int* f) {
        for (;;) {
            unsigned v = 0;
            if (lane == 0)
                v = __hip_atomic_load(f, __ATOMIC_RELAXED, __HIP_MEMORY_SCOPE_SYSTEM);
            v = (unsigned)__builtin_amdgcn_readfirstlane((int)v);
            if (v >= 8u) return;
            __builtin_amdgcn_s_sleep(1);
        }
    };

    for (int t = 0; t < TSTEPS; ++t) {
        const int slot = t & (RING - 1);
        const int eb   = (tid & 15) * 16;   // 16-elem group within a 256 row

        // ---- all cross-block waits first, then ONE acquire fence ----
        if (l > 0) wait8(fl_up + t);                       // x-half ready
        if (t > 0) wait8(fl_own + (t - 1));                // own h(t-1) ready
        if (l < 3 && t >= RING) wait8(fl_dn + (t - RING)); // ring backpressure
        __builtin_amdgcn_fence(__ATOMIC_ACQUIRE, "");      // system acquire (inv)

        // ---- x-half: layer l-1 output at t (or global x for l==0) ----
        ull   xr[4];
        f32x4 xf0, xf1, xf2, xf3;
        if (tid < 256) {
            if (l == 0) {
                const float* sp = x + ((size_t)(b0row + grow) * TSTEPS + t) * 256 + eb;
                xf0 = *(const f32x4*)sp;       xf1 = *(const f32x4*)(sp + 4);
                xf2 = *(const f32x4*)(sp + 8); xf3 = *(const f32x4*)(sp + 12);
            } else {
                const ull* sp = (const ull*)(hb_up + ((size_t)slot * 16 + grow) * 256 + eb);
                xr[0] = sp[0]; xr[1] = sp[1]; xr[2] = sp[2]; xr[3] = sp[3];
            }
        }

        // ---- h-half: own group's h_{t-1} ----
        ull hr[4] = {0ull, 0ull, 0ull, 0ull};
        if (t > 0 && tid < 256) {
            const ull* sp = (const ull*)(hb_own + ((size_t)((t - 1) & (RING - 1)) * 16 + grow) * 256 + eb);
            hr[0] = sp[0]; hr[1] = sp[1]; hr[2] = sp[2]; hr[3] = sp[3];
        }

        // ---- build A = [x | h] in LDS ----
        if (tid < 256) {
            _Float16* arow = Ash + grow * AP2;
            if (l == 0) {
                half8 h0, h1;
                h0[0]=(_Float16)xf0[0]; h0[1]=(_Float16)xf0[1]; h0[2]=(_Float16)xf0[2]; h0[3]=(_Float16)xf0[3];
                h0[4]=(_Float16)xf1[0]; h0[5]=(_Float16)xf1[1]; h0[6]=(_Float16)xf1[2]; h0[7]=(_Float16)xf1[3];
                h1[0]=(_Float16)xf2[0]; h1[1]=(_Float16)xf2[1]; h1[2]=(_Float16)xf2[2]; h1[3]=(_Float16)xf2[3];
                h1[4]=(_Float16)xf3[0]; h1[5]=(_Float16)xf3[1]; h1[6]=(_Float16)xf3[2]; h1[7]=(_Float16)xf3[3];
                *(half8*)(arow + eb)     = h0;
                *(half8*)(arow + eb + 8) = h1;
            } else {
                *(ull*)(arow + eb)      = xr[0];
                *(ull*)(arow + eb + 4)  = xr[1];
                *(ull*)(arow + eb + 8)  = xr[2];
                *(ull*)(arow + eb + 12) = xr[3];
            }
            *(ull*)(arow + 256 + eb)      = hr[0];
            *(ull*)(arow + 256 + eb + 4)  = hr[1];
            *(ull*)(arow + 256 + eb + 8)  = hr[2];
            *(ull*)(arow + 256 + eb + 12) = hr[3];
        }
        __syncthreads();   // B1: A complete

        // ---- MFMA: wave w computes its 16-col tile over K=512 ----
        f32x4 acc0 = {0,0,0,0}, acc1 = {0,0,0,0};
        const _Float16* wl = Wlds + (size_t)w * (16 * 64 * 8);
#pragma unroll
        for (int kt = 0; kt < 16; ++kt) {
            half8 a = *(const half8*)(Ash + lo16 * AP2 + q * 8 + kt * 32);
            half8 b = *(const half8*)(wl + ((size_t)kt * 64 + lane) * 8);
            if (w < 4 || kt < 8)
                acc0 = __builtin_amdgcn_mfma_f32_16x16x32_f16(a, b, acc0, 0, 0, 0);
            else
                acc1 = __builtin_amdgcn_mfma_f32_16x16x32_f16(a, b, acc1, 0, 0, 0);
        }
#pragma unroll
        for (int r = 0; r < 4; ++r) Sc[w][q * 4 + r][lo16] = acc0[r];
        if (w >= 4) {
#pragma unroll
            for (int r = 0; r < 4; ++r) Sc[w + 2][q * 4 + r][lo16] = acc1[r];
        }
        __syncthreads();   // B2: Sc complete

        // ---- gates: z=sig, r=sig, hh=tanh(mh + r*rhh); h fp32 in regs ----
        if (tid < 256) {
            float hn[2];
#pragma unroll
            for (int j = 0; j < 2; ++j) {
                int u   = gup + j;
                int ut  = u >> 4;
                int col = u & 15;
                float zp = Sc[ut][grow][col]     + bz[j];
                float rp = Sc[2 + ut][grow][col] + br[j];
                float ip = Sc[4 + ut][grow][col] + bi[j];
                float hp = Sc[6 + ut][grow][col] + bh[j];
                float z  = 1.f / (1.f + __expf(-zp));
                float rr = 1.f / (1.f + __expf(-rp));
                float pre = ip + rr * hp;
                float e  = __expf(2.f * pre);
                float th = 1.f - 2.f / (e + 1.f);
                hn[j] = z * hprev[j] + (1.f - z) * th;
                hprev[j] = hn[j];
            }
            union { _Float16 h[2]; unsigned u32; } pk;
            pk.h[0] = (_Float16)hn[0];
            pk.h[1] = (_Float16)hn[1];
            // plain store; made visible by the release fence below
            *(unsigned*)(hb_own + ((size_t)slot * 16 + grow) * 256 + s * 32 + gup) = pk.u32;
            if (l == 3 && t == TSTEPS - 1) {
                float* op = out + (size_t)(b0row + grow) * 256 + s * 32 + gup;
                op[0] = hn[0];
                op[1] = hn[1];
            }
        }
        __syncthreads();   // B3: every wave's stores vmcnt-drained before barrier

        if (tid == 0) {
            // system release: waitcnt + L2 writeback, tracked to completion,
            // THEN the flag RMW — data guaranteed at the coherence point first.
            __builtin_amdgcn_fence(__ATOMIC_RELEASE, "");
            __hip_atomic_fetch_add(fl_own + t, 1u, __ATOMIC_RELAXED, __HIP_MEMORY_SCOPE_SYSTEM);
        }
    }
}

extern "C" void kernel_launch(void* const* d_in, const int* in_sizes, int n_in,
                              void* d_out, int out_size, void* d_ws, size_t ws_size,
                              hipStream_t stream)
{
    const float* x     = (const float*)d_in[0];
    const float* k0    = (const float*)d_in[1];
    const float* rk0   = (const float*)d_in[2];
    const float* b0    = (const float*)d_in[3];
    const float* kern  = (const float*)d_in[4];
    const float* rkern = (const float*)d_in[5];
    const float* bias  = (const float*)d_in[6];
    float* out = (float*)d_out;

    char* ws = (char*)d_ws;
    _Float16*     Wp    = (_Float16*)(ws + WP_OFF);
    float*        Bp    = (float*)(ws + BP_OFF);
    unsigned int* flags = (unsigned int*)(ws + FLAG_OFF);
    _Float16*     hbuf  = (_Float16*)(ws + HBUF_OFF);

    hipMemsetAsync(flags, 0, FLAG_BYTES, stream);

    const int total = LAYERS * WPL + LAYERS * 1024;
    repack_kernel<<<(total + 255) / 256, 256, 0, stream>>>(k0, rk0, b0, kern, rkern, bias, Wp, Bp);

    gru_kernel<<<LAYERS * NCH * 8, 384, 0, stream>>>(x, Wp, Bp, hbuf, flags, out);
}

// Round 6
// 1752.487 us; speedup vs baseline: 3.7570x; 3.7570x over previous
//
#include <hip/hip_runtime.h>
#include <hip/hip_fp16.h>

// ---------------------------------------------------------------------------
// 4-layer GRU stack (Keras reset_after), B=128, T=384, U=D=256.
// 256 persistent blocks = 4 layers x 8 chunks(16 rows) x 8 unit-slices(32 u).
// Weight B-fragments in REGISTERS (64 VGPRs/wave). Per step: M=16,N=96,K=512.
// Cross-block h exchange: EPOCH-TAGGED 8-byte words in a 16-deep MALL ring.
// Each ull = {epoch(32) | h1(16) | h0(16)}, stored with one relaxed
// system-scope atomic -> tag+data atomic. Consumers spin on the DATA until
// epoch matches; no flag/data ordering assumptions anywhere (8 slice blocks
// sit on 8 different XCDs -> cross-XCD store order is NOT guaranteed; round 5
// failed exactly on that). Flags remain only as ring backpressure, where
// staleness merely delays the producer (read-then-flag can't overstate).
// ---------------------------------------------------------------------------

#define LAYERS 4
#define TSTEPS 384
#define NCH    8
#define AP2    520                 // A row pitch (512 + 8 pad) in fp16 elems
#define WPL    (48 * 16 * 64 * 8)  // repacked weight elems per layer
#define TILE_STRIDE (16 * 64 * 8)  // 8192 elems per 16-col tile
#define RING   16
#define SLOT_ULL (16 * 128)        // 16 rows x 128 tagged ulls per slot
#define GRP_ULL  (RING * SLOT_ULL) // 32768 ulls (256 KB) per (l,c) group

typedef _Float16 half8 __attribute__((ext_vector_type(8)));
typedef float    f32x4 __attribute__((ext_vector_type(4)));
typedef unsigned long long ull;

// ws layout (bytes)
#define WP_OFF   0
#define BP_OFF   (LAYERS * WPL * 2)                 // 3,145,728
#define FLAG_OFF (BP_OFF + LAYERS * 1024 * 4)       // +16 KB
#define FLAG_BYTES 4096                             // 32 groups x 64 B (+pad)
#define HBUF_OFF (4 * 1024 * 1024)                  // 8 MB of tagged ring

// ---------------------------------------------------------------------------
// Repack: W[l] -> [tile=48][kt=16][lane=64][8] fp16 B-fragments.
// n = tile*16 + (lane&15), k = kt*32 + (lane>>4)*8 + j; k<256 input kernel,
// k>=256 recurrent. Bias: [0:512]=b_in+b_rec (z,r), [512:768]=b_in_h,
// [768:1024]=b_rec_h.
// ---------------------------------------------------------------------------
__global__ void repack_kernel(const float* __restrict__ k0, const float* __restrict__ rk0,
                              const float* __restrict__ b0, const float* __restrict__ kern,
                              const float* __restrict__ rkern, const float* __restrict__ bias,
                              _Float16* __restrict__ Wp, float* __restrict__ Bp)
{
    int idx = blockIdx.x * 256 + threadIdx.x;
    const int total_w = LAYERS * WPL;
    if (idx < total_w) {
        int l = idx / WPL;
        int r = idx - l * WPL;
        int j    = r & 7;
        int lane = (r >> 3) & 63;
        int kt   = (r >> 9) & 15;
        int tile = r >> 13;
        int n = tile * 16 + (lane & 15);
        int k = kt * 32 + (lane >> 4) * 8 + j;
        float v;
        if (l == 0) {
            v = (k < 256) ? k0[(size_t)k * 768 + n] : rk0[(size_t)(k - 256) * 768 + n];
        } else {
            const float* kk = kern  + (size_t)(l - 1) * 256 * 768;
            const float* rk = rkern + (size_t)(l - 1) * 256 * 768;
            v = (k < 256) ? kk[(size_t)k * 768 + n] : rk[(size_t)(k - 256) * 768 + n];
        }
        Wp[idx] = (_Float16)v;
    } else {
        int ib = idx - total_w;
        if (ib < LAYERS * 1024) {
            int l = ib >> 10;
            int i = ib & 1023;
            const float* bs = (l == 0) ? b0 : (bias + (size_t)(l - 1) * 2 * 768);
            float v;
            if (i < 512)      v = bs[i] + bs[768 + i];
            else if (i < 768) v = bs[512 + (i - 512)];
            else              v = bs[768 + 512 + (i - 768)];
            Bp[l * 1024 + i] = v;
        }
    }
}

// ---------------------------------------------------------------------------
// Persistent GRU kernel: 384 threads = 6 waves; wave w computes one 16-col
// tile: w0,w1=z  w2,w3=r  w4,w5=h (split accumulators k<256 / k>=256).
// ---------------------------------------------------------------------------
__launch_bounds__(384, 1)
__global__ void gru_kernel(const float* __restrict__ x,
                           const _Float16* __restrict__ Wp,
                           const float* __restrict__ Bp,
                           ull* __restrict__ hbuf,
                           unsigned int* __restrict__ flags,
                           float* __restrict__ out)
{
    __shared__ _Float16 Ash[16 * AP2];           // 16.6 KB
    __shared__ float    Sc[8][16][17];           // 8.7 KB

    const int tid  = threadIdx.x;
    const int lane = tid & 63;
    const int w    = tid >> 6;
    const int lo16 = lane & 15;
    const int q    = lane >> 4;

    const int s = blockIdx.x & 7;          // unit slice
    const int c = (blockIdx.x >> 3) & 7;   // batch chunk
    const int l = blockIdx.x >> 6;         // layer
    const int b0row = c * 16;

    // ---- this wave's weight tile -> registers (once) ----
    const int tile = (w >> 1) * 16 + 2 * s + (w & 1);
    half8 bfrag[16];
    {
        const _Float16* wb = Wp + (size_t)l * WPL + (size_t)tile * TILE_STRIDE;
#pragma unroll
        for (int kt = 0; kt < 16; ++kt)
            bfrag[kt] = *(const half8*)(wb + ((size_t)kt * 64 + lane) * 8);
    }

    // ---- per-gate-thread constants (tid<256: row=tid>>4, units gup,gup+1) ----
    const int grow = tid >> 4;
    const int g16  = tid & 15;
    const int gup  = g16 * 2;
    float bz[2] = {0,0}, br[2] = {0,0}, bi[2] = {0,0}, bh[2] = {0,0};
    float hprev[2] = {0.f, 0.f};
    if (tid < 256) {
        const float* bp = Bp + l * 1024;
        int ug = s * 32 + gup;
        bz[0] = bp[ug];       bz[1] = bp[ug + 1];
        br[0] = bp[256 + ug]; br[1] = bp[256 + ug + 1];
        bi[0] = bp[512 + ug]; bi[1] = bp[512 + ug + 1];
        bh[0] = bp[768 + ug]; bh[1] = bp[768 + ug + 1];
    }

    // ---- backpressure flags: 8 per group (one per slice), 64 B/group ----
    unsigned int* fl_own_g = flags + (l * NCH + c) * 16;
    unsigned int* fl_dn_g  = flags + ((l < 3 ? l + 1 : 0) * NCH + c) * 16;
    unsigned int* my_flag  = fl_own_g + s;

    ull*       hb_own = hbuf + (size_t)(l * NCH + c) * GRP_ULL;
    const ull* hb_up  = hbuf + (size_t)((l > 0 ? l - 1 : 0) * NCH + c) * GRP_ULL;

    auto wait_group = [&](const unsigned int* base, unsigned need) {
        for (;;) {
            unsigned v = 0xFFFFFFFFu;
            if (lane < 8)
                v = __hip_atomic_load(base + lane, __ATOMIC_RELAXED,
                                      __HIP_MEMORY_SCOPE_SYSTEM);
            if (__all((int)(v >= need))) return;
            __builtin_amdgcn_s_sleep(1);
        }
    };

    for (int t = 0; t < TSTEPS; ++t) {
        const int slot  = t & (RING - 1);
        const int pslot = (t - 1) & (RING - 1);
        const bool need_xt = (l > 0);            // tagged x from upstream ring
        const bool need_h  = (t > 0);
        const unsigned xtag = (unsigned)(t + 1); // upstream wrote epoch t+1
        const unsigned htag = (unsigned)t;       // own group wrote epoch t

        // ---- issue all tagged loads together (16 in flight), then validate ----
        ull vx[8], vh[8];
        f32x4 xf0, xf1, xf2, xf3;
        if (tid < 256) {
            const ull* spx = hb_up  + (size_t)slot  * SLOT_ULL + grow * 128 + g16 * 8;
            const ull* sph = hb_own + (size_t)pslot * SLOT_ULL + grow * 128 + g16 * 8;
            if (need_xt) {
#pragma unroll
                for (int j = 0; j < 8; ++j)
                    vx[j] = __hip_atomic_load(spx + j, __ATOMIC_RELAXED, __HIP_MEMORY_SCOPE_SYSTEM);
            } else {
                const float* sp = x + ((size_t)(b0row + grow) * TSTEPS + t) * 256 + gup * 8;
                xf0 = *(const f32x4*)sp;       xf1 = *(const f32x4*)(sp + 4);
                xf2 = *(const f32x4*)(sp + 8); xf3 = *(const f32x4*)(sp + 12);
            }
            if (need_h) {
#pragma unroll
                for (int j = 0; j < 8; ++j)
                    vh[j] = __hip_atomic_load(sph + j, __ATOMIC_RELAXED, __HIP_MEMORY_SCOPE_SYSTEM);
            }
            for (;;) {
                bool ok = true;
                if (need_xt) {
#pragma unroll
                    for (int j = 0; j < 8; ++j)
                        if ((unsigned)(vx[j] >> 32) != xtag) {
                            vx[j] = __hip_atomic_load(spx + j, __ATOMIC_RELAXED, __HIP_MEMORY_SCOPE_SYSTEM);
                            ok = false;
                        }
                }
                if (need_h) {
#pragma unroll
                    for (int j = 0; j < 8; ++j)
                        if ((unsigned)(vh[j] >> 32) != htag) {
                            vh[j] = __hip_atomic_load(sph + j, __ATOMIC_RELAXED, __HIP_MEMORY_SCOPE_SYSTEM);
                            ok = false;
                        }
                }
                if (ok) break;
            }
        }

        // ---- ring backpressure: downstream consumed slot t-RING ----
        if (l < 3 && t >= RING) wait_group(fl_dn_g, (unsigned)(t - RING + 1));

        // ---- build A = [x | h] in LDS ----
        if (tid < 256) {
            _Float16* arow = Ash + grow * AP2;
            const int eb = g16 * 16;
            if (need_xt) {
#pragma unroll
                for (int j = 0; j < 8; ++j)
                    *(unsigned*)(arow + eb + 2 * j) = (unsigned)vx[j];
            } else {
                half8 h0, h1;
                h0[0]=(_Float16)xf0[0]; h0[1]=(_Float16)xf0[1]; h0[2]=(_Float16)xf0[2]; h0[3]=(_Float16)xf0[3];
                h0[4]=(_Float16)xf1[0]; h0[5]=(_Float16)xf1[1]; h0[6]=(_Float16)xf1[2]; h0[7]=(_Float16)xf1[3];
                h1[0]=(_Float16)xf2[0]; h1[1]=(_Float16)xf2[1]; h1[2]=(_Float16)xf2[2]; h1[3]=(_Float16)xf2[3];
                h1[4]=(_Float16)xf3[0]; h1[5]=(_Float16)xf3[1]; h1[6]=(_Float16)xf3[2]; h1[7]=(_Float16)xf3[3];
                *(half8*)(arow + eb)     = h0;
                *(half8*)(arow + eb + 8) = h1;
            }
            if (need_h) {
#pragma unroll
                for (int j = 0; j < 8; ++j)
                    *(unsigned*)(arow + 256 + eb + 2 * j) = (unsigned)vh[j];
            } else {
#pragma unroll
                for (int j = 0; j < 8; ++j)
                    *(unsigned*)(arow + 256 + eb + 2 * j) = 0u;
            }
        }
        __syncthreads();   // B1: A complete

        // ---- MFMA: wave w computes its 16-col tile over K=512 (B in regs) ----
        f32x4 acc0 = {0,0,0,0}, acc1 = {0,0,0,0};
#pragma unroll
        for (int kt = 0; kt < 16; ++kt) {
            half8 a = *(const half8*)(Ash + lo16 * AP2 + q * 8 + kt * 32);
            if (w < 4 || kt < 8)
                acc0 = __builtin_amdgcn_mfma_f32_16x16x32_f16(a, bfrag[kt], acc0, 0, 0, 0);
            else
                acc1 = __builtin_amdgcn_mfma_f32_16x16x32_f16(a, bfrag[kt], acc1, 0, 0, 0);
        }
#pragma unroll
        for (int r = 0; r < 4; ++r) Sc[w][q * 4 + r][lo16] = acc0[r];
        if (w >= 4) {
#pragma unroll
            for (int r = 0; r < 4; ++r) Sc[w + 2][q * 4 + r][lo16] = acc1[r];
        }
        __syncthreads();   // B2: Sc complete

        // ---- gates: z=sig, r=sig, hh=tanh(mh + r*rhh); h fp32 in regs ----
        if (tid < 256) {
            float hn[2];
#pragma unroll
            for (int j = 0; j < 2; ++j) {
                int u   = gup + j;
                int ut  = u >> 4;
                int col = u & 15;
                float zp = Sc[ut][grow][col]     + bz[j];
                float rp = Sc[2 + ut][grow][col] + br[j];
                float ip = Sc[4 + ut][grow][col] + bi[j];
                float hp = Sc[6 + ut][grow][col] + bh[j];
                float z  = 1.f / (1.f + __expf(-zp));
                float rr = 1.f / (1.f + __expf(-rp));
                float pre = ip + rr * hp;
                float e  = __expf(2.f * pre);
                float th = 1.f - 2.f / (e + 1.f);
                hn[j] = z * hprev[j] + (1.f - z) * th;
                hprev[j] = hn[j];
            }
            union { _Float16 h[2]; unsigned u32; } pk;
            pk.h[0] = (_Float16)hn[0];
            pk.h[1] = (_Float16)hn[1];
            // epoch-tagged 8-byte atomic store: tag+data arrive together
            ull word = ((ull)(unsigned)(t + 1) << 32) | (ull)pk.u32;
            __hip_atomic_store(hb_own + (size_t)slot * SLOT_ULL + grow * 128 + s * 16 + g16,
                               word, __ATOMIC_RELAXED, __HIP_MEMORY_SCOPE_SYSTEM);
            if (l == 3 && t == TSTEPS - 1) {
                float* op = out + (size_t)(b0row + grow) * 256 + s * 32 + gup;
                op[0] = hn[0];
                op[1] = hn[1];
            }
        }
        __syncthreads();   // B3: step complete (all loads of step t consumed)

        // backpressure publish: value never overstates (loads done in-register)
        if (tid == 0)
            __hip_atomic_store(my_flag, (unsigned)(t + 1),
                               __ATOMIC_RELAXED, __HIP_MEMORY_SCOPE_SYSTEM);
    }
}

extern "C" void kernel_launch(void* const* d_in, const int* in_sizes, int n_in,
                              void* d_out, int out_size, void* d_ws, size_t ws_size,
                              hipStream_t stream)
{
    const float* x     = (const float*)d_in[0];
    const float* k0    = (const float*)d_in[1];
    const float* rk0   = (const float*)d_in[2];
    const float* b0    = (const float*)d_in[3];
    const float* kern  = (const float*)d_in[4];
    const float* rkern = (const float*)d_in[5];
    const float* bias  = (const float*)d_in[6];
    float* out = (float*)d_out;

    char* ws = (char*)d_ws;
    _Float16*     Wp    = (_Float16*)(ws + WP_OFF);
    float*        Bp    = (float*)(ws + BP_OFF);
    unsigned int* flags = (unsigned int*)(ws + FLAG_OFF);
    ull*          hbuf  = (ull*)(ws + HBUF_OFF);

    hipMemsetAsync(flags, 0, FLAG_BYTES, stream);

    const int total = LAYERS * WPL + LAYERS * 1024;
    repack_kernel<<<(total + 255) / 256, 256, 0, stream>>>(k0, rk0, b0, kern, rkern, bias, Wp, Bp);

    gru_kernel<<<LAYERS * NCH * 8, 384, 0, stream>>>(x, Wp, Bp, hbuf, flags, out);
}

// Round 7
// 1652.829 us; speedup vs baseline: 3.9835x; 1.0603x over previous
//
#include <hip/hip_runtime.h>
#include <hip/hip_fp16.h>

// ---------------------------------------------------------------------------
// 4-layer GRU stack (Keras reset_after), B=128, T=384, U=D=256.
// 256 persistent blocks = 4 layers x 8 chunks(16 rows) x 8 unit-slices(32 u).
// Weight B-fragments in REGISTERS (64 VGPRs/wave). Per step: M=16,N=96,K=512.
// A is stored in LDS in MFMA FRAGMENT ORDER (Af[kt][lane][8]) so the a-frag
// read is a wave-contiguous ds_read_b128 (conflict-free).
// Cross-block h exchange: epoch-tagged 8-byte words ({epoch|h1|h0}) in a
// 16-deep MALL ring, relaxed system-scope atomics; consumers spin on the
// DATA tags (self-validating — no flag/data ordering assumptions).
// Critical path = own-h only: upstream-x(t+1) is validated+staged at the END
// of step t (after h-publish); own-h loads are PREFETCHED at end of step t
// and validated at start of t+1. Flags only for ring backpressure.
// ---------------------------------------------------------------------------

#define LAYERS 4
#define TSTEPS 384
#define NCH    8
#define WPL    (48 * 16 * 64 * 8)  // repacked weight elems per layer
#define TILE_STRIDE (16 * 64 * 8)  // 8192 elems per 16-col tile
#define RING   16
#define SLOT_ULL (16 * 128)        // 16 rows x 128 tagged ulls per slot
#define GRP_ULL  (RING * SLOT_ULL)

typedef _Float16 half8 __attribute__((ext_vector_type(8)));
typedef float    f32x4 __attribute__((ext_vector_type(4)));
typedef unsigned uint4v __attribute__((ext_vector_type(4)));
typedef unsigned long long ull;

// ws layout (bytes)
#define WP_OFF   0
#define BP_OFF   (LAYERS * WPL * 2)                 // 3,145,728
#define FLAG_OFF (BP_OFF + LAYERS * 1024 * 4)       // +16 KB
#define FLAG_BYTES 4096
#define HBUF_OFF (4 * 1024 * 1024)

// ---------------------------------------------------------------------------
// Repack: W[l] -> [tile=48][kt=16][lane=64][8] fp16 B-fragments.
// n = tile*16 + (lane&15), k = kt*32 + (lane>>4)*8 + j.
// Bias: [0:512]=b_in+b_rec (z,r), [512:768]=b_in_h, [768:1024]=b_rec_h.
// ---------------------------------------------------------------------------
__global__ void repack_kernel(const float* __restrict__ k0, const float* __restrict__ rk0,
                              const float* __restrict__ b0, const float* __restrict__ kern,
                              const float* __restrict__ rkern, const float* __restrict__ bias,
                              _Float16* __restrict__ Wp, float* __restrict__ Bp)
{
    int idx = blockIdx.x * 256 + threadIdx.x;
    const int total_w = LAYERS * WPL;
    if (idx < total_w) {
        int l = idx / WPL;
        int r = idx - l * WPL;
        int j    = r & 7;
        int lane = (r >> 3) & 63;
        int kt   = (r >> 9) & 15;
        int tile = r >> 13;
        int n = tile * 16 + (lane & 15);
        int k = kt * 32 + (lane >> 4) * 8 + j;
        float v;
        if (l == 0) {
            v = (k < 256) ? k0[(size_t)k * 768 + n] : rk0[(size_t)(k - 256) * 768 + n];
        } else {
            const float* kk = kern  + (size_t)(l - 1) * 256 * 768;
            const float* rk = rkern + (size_t)(l - 1) * 256 * 768;
            v = (k < 256) ? kk[(size_t)k * 768 + n] : rk[(size_t)(k - 256) * 768 + n];
        }
        Wp[idx] = (_Float16)v;
    } else {
        int ib = idx - total_w;
        if (ib < LAYERS * 1024) {
            int l = ib >> 10;
            int i = ib & 1023;
            const float* bs = (l == 0) ? b0 : (bias + (size_t)(l - 1) * 2 * 768);
            float v;
            if (i < 512)      v = bs[i] + bs[768 + i];
            else if (i < 768) v = bs[512 + (i - 512)];
            else              v = bs[768 + 512 + (i - 768)];
            Bp[l * 1024 + i] = v;
        }
    }
}

// ---------------------------------------------------------------------------
// Persistent GRU kernel: 384 threads = 6 waves; wave w computes one 16-col
// tile: w0,w1=z  w2,w3=r  w4,w5=h (split accumulators k<256 / k>=256).
// ---------------------------------------------------------------------------
__launch_bounds__(384, 1)
__global__ void gru_kernel(const float* __restrict__ x,
                           const _Float16* __restrict__ Wp,
                           const float* __restrict__ Bp,
                           ull* __restrict__ hbuf,
                           unsigned int* __restrict__ flags,
                           float* __restrict__ out)
{
    __shared__ _Float16 Af[2][16 * 512];   // fragment-ordered A, 16 KB each
    __shared__ float    Sc[8][16][17];     // 8.7 KB

    const int tid  = threadIdx.x;
    const int lane = tid & 63;
    const int w    = tid >> 6;
    const int lo16 = lane & 15;
    const int q    = lane >> 4;

    const int s = blockIdx.x & 7;          // unit slice
    const int c = (blockIdx.x >> 3) & 7;   // batch chunk
    const int l = blockIdx.x >> 6;         // layer
    const int b0row = c * 16;

    // ---- this wave's weight tile -> registers (once) ----
    const int tile = (w >> 1) * 16 + 2 * s + (w & 1);
    half8 bfrag[16];
    {
        const _Float16* wb = Wp + (size_t)l * WPL + (size_t)tile * TILE_STRIDE;
#pragma unroll
        for (int kt = 0; kt < 16; ++kt)
            bfrag[kt] = *(const half8*)(wb + ((size_t)kt * 64 + lane) * 8);
    }

    // ---- per-gate-thread mapping (tid<256: row grow, units gup,gup+1) ----
    const int grow = tid >> 4;
    const int g16  = tid & 15;
    const int gup  = g16 * 2;
    // fragment-store offsets for this thread's 16 k-elems (2 half8 groups)
    const int ktx  = g16 >> 1;
    const int qq   = (g16 & 1) * 2;
    const int xoff0 = ((ktx * 64) + qq * 16 + grow) * 8;
    const int xoff1 = ((ktx * 64) + (qq + 1) * 16 + grow) * 8;
    const int hoff0 = (((8 + ktx) * 64) + qq * 16 + grow) * 8;
    const int hoff1 = (((8 + ktx) * 64) + (qq + 1) * 16 + grow) * 8;

    float bz[2] = {0,0}, br[2] = {0,0}, bi[2] = {0,0}, bh[2] = {0,0};
    float hprev[2] = {0.f, 0.f};
    if (tid < 256) {
        const float* bp = Bp + l * 1024;
        int ug = s * 32 + gup;
        bz[0] = bp[ug];       bz[1] = bp[ug + 1];
        br[0] = bp[256 + ug]; br[1] = bp[256 + ug + 1];
        bi[0] = bp[512 + ug]; bi[1] = bp[512 + ug + 1];
        bh[0] = bp[768 + ug]; bh[1] = bp[768 + ug + 1];
    }

    unsigned int* fl_own_g = flags + (l * NCH + c) * 16;
    unsigned int* fl_dn_g  = flags + ((l < 3 ? l + 1 : 0) * NCH + c) * 16;
    unsigned int* my_flag  = fl_own_g + s;

    ull*       hb_own = hbuf + (size_t)(l * NCH + c) * GRP_ULL;
    const ull* hb_up  = hbuf + (size_t)((l > 0 ? l - 1 : 0) * NCH + c) * GRP_ULL;

    auto wait_group = [&](const unsigned int* base, unsigned need) {
        for (;;) {
            unsigned v = 0xFFFFFFFFu;
            if (lane < 8)
                v = __hip_atomic_load(base + lane, __ATOMIC_RELAXED,
                                      __HIP_MEMORY_SCOPE_SYSTEM);
            if (__all((int)(v >= need))) return;
            __builtin_amdgcn_s_sleep(1);
        }
    };

    auto stage_x = [&](int t, _Float16* An) {   // stage x(t) into An (tid<256)
        if (l == 0) {
            const float* sp = x + ((size_t)(b0row + grow) * TSTEPS + t) * 256 + gup * 8;
            f32x4 a0 = *(const f32x4*)sp,      a1 = *(const f32x4*)(sp + 4);
            f32x4 a2 = *(const f32x4*)(sp + 8), a3 = *(const f32x4*)(sp + 12);
            half8 h0, h1;
            h0[0]=(_Float16)a0[0]; h0[1]=(_Float16)a0[1]; h0[2]=(_Float16)a0[2]; h0[3]=(_Float16)a0[3];
            h0[4]=(_Float16)a1[0]; h0[5]=(_Float16)a1[1]; h0[6]=(_Float16)a1[2]; h0[7]=(_Float16)a1[3];
            h1[0]=(_Float16)a2[0]; h1[1]=(_Float16)a2[1]; h1[2]=(_Float16)a2[2]; h1[3]=(_Float16)a2[3];
            h1[4]=(_Float16)a3[0]; h1[5]=(_Float16)a3[1]; h1[6]=(_Float16)a3[2]; h1[7]=(_Float16)a3[3];
            *(half8*)(An + xoff0) = h0;
            *(half8*)(An + xoff1) = h1;
        } else {
            const ull* spx = hb_up + (size_t)(t & (RING - 1)) * SLOT_ULL + grow * 128 + g16 * 8;
            const unsigned tg = (unsigned)(t + 1);
            ull vx[8];
#pragma unroll
            for (int j = 0; j < 8; ++j)
                vx[j] = __hip_atomic_load(spx + j, __ATOMIC_RELAXED, __HIP_MEMORY_SCOPE_SYSTEM);
            for (;;) {
                bool ok = true;
#pragma unroll
                for (int j = 0; j < 8; ++j)
                    if ((unsigned)(vx[j] >> 32) != tg) {
                        vx[j] = __hip_atomic_load(spx + j, __ATOMIC_RELAXED, __HIP_MEMORY_SCOPE_SYSTEM);
                        ok = false;
                    }
                if (ok) break;
                __builtin_amdgcn_s_sleep(1);
            }
            uint4v w0, w1;
            w0[0]=(unsigned)vx[0]; w0[1]=(unsigned)vx[1]; w0[2]=(unsigned)vx[2]; w0[3]=(unsigned)vx[3];
            w1[0]=(unsigned)vx[4]; w1[1]=(unsigned)vx[5]; w1[2]=(unsigned)vx[6]; w1[3]=(unsigned)vx[7];
            *(uint4v*)(An + xoff0) = w0;
            *(uint4v*)(An + xoff1) = w1;
        }
    };

    // ---- prologue: x(0) + zero h into Af[0] ----
    if (tid < 256) {
        stage_x(0, Af[0]);
        uint4v z = {0u, 0u, 0u, 0u};
        *(uint4v*)(Af[0] + hoff0) = z;
        *(uint4v*)(Af[0] + hoff1) = z;
    }

    ull vh[8];   // prefetched own-h tagged words

    for (int t = 0; t < TSTEPS; ++t) {
        _Float16* A  = Af[t & 1];
        _Float16* An = Af[(t + 1) & 1];

        // ---- stage 1: validate prefetched own-h(t-1), stage into A ----
        if (t > 0 && tid < 256) {
            const ull* sph = hb_own + (size_t)((t - 1) & (RING - 1)) * SLOT_ULL + grow * 128 + g16 * 8;
            const unsigned tg = (unsigned)t;
            for (;;) {
                bool ok = true;
#pragma unroll
                for (int j = 0; j < 8; ++j)
                    if ((unsigned)(vh[j] >> 32) != tg) {
                        vh[j] = __hip_atomic_load(sph + j, __ATOMIC_RELAXED, __HIP_MEMORY_SCOPE_SYSTEM);
                        ok = false;
                    }
                if (ok) break;
            }
            uint4v w0, w1;
            w0[0]=(unsigned)vh[0]; w0[1]=(unsigned)vh[1]; w0[2]=(unsigned)vh[2]; w0[3]=(unsigned)vh[3];
            w1[0]=(unsigned)vh[4]; w1[1]=(unsigned)vh[5]; w1[2]=(unsigned)vh[6]; w1[3]=(unsigned)vh[7];
            *(uint4v*)(A + hoff0) = w0;
            *(uint4v*)(A + hoff1) = w1;
        }
        __syncthreads();   // B1: A complete

        // ---- stage 2: MFMA, a-frag = wave-contiguous ds_read_b128 ----
        f32x4 acc0 = {0,0,0,0}, acc1 = {0,0,0,0};
#pragma unroll
        for (int kt = 0; kt < 16; ++kt) {
            half8 a = *(const half8*)(A + ((kt * 64) + lane) * 8);
            if (w < 4 || kt < 8)
                acc0 = __builtin_amdgcn_mfma_f32_16x16x32_f16(a, bfrag[kt], acc0, 0, 0, 0);
            else
                acc1 = __builtin_amdgcn_mfma_f32_16x16x32_f16(a, bfrag[kt], acc1, 0, 0, 0);
        }
#pragma unroll
        for (int r = 0; r < 4; ++r) Sc[w][q * 4 + r][lo16] = acc0[r];
        if (w >= 4) {
#pragma unroll
            for (int r = 0; r < 4; ++r) Sc[w + 2][q * 4 + r][lo16] = acc1[r];
        }
        __syncthreads();   // B2: Sc complete

        // ---- ring backpressure before overwriting slot t ----
        if (l < 3 && t >= RING) wait_group(fl_dn_g, (unsigned)(t - RING + 1));

        // ---- stage 5: gates; publish tagged h(t) immediately ----
        if (tid < 256) {
            float hn[2];
#pragma unroll
            for (int j = 0; j < 2; ++j) {
                int u   = gup + j;
                int ut  = u >> 4;
                int col = u & 15;
                float zp = Sc[ut][grow][col]     + bz[j];
                float rp = Sc[2 + ut][grow][col] + br[j];
                float ip = Sc[4 + ut][grow][col] + bi[j];
                float hp = Sc[6 + ut][grow][col] + bh[j];
                float z  = 1.f / (1.f + __expf(-zp));
                float rr = 1.f / (1.f + __expf(-rp));
                float pre = ip + rr * hp;
                float e  = __expf(2.f * pre);
                float th = 1.f - 2.f / (e + 1.f);
                hn[j] = z * hprev[j] + (1.f - z) * th;
                hprev[j] = hn[j];
            }
            union { _Float16 h[2]; unsigned u32; } pk;
            pk.h[0] = (_Float16)hn[0];
            pk.h[1] = (_Float16)hn[1];
            ull word = ((ull)(unsigned)(t + 1) << 32) | (ull)pk.u32;
            __hip_atomic_store(hb_own + (size_t)(t & (RING - 1)) * SLOT_ULL + grow * 128 + s * 16 + g16,
                               word, __ATOMIC_RELAXED, __HIP_MEMORY_SCOPE_SYSTEM);
            if (l == 3 && t == TSTEPS - 1) {
                float* op = out + (size_t)(b0row + grow) * 256 + s * 32 + gup;
                op[0] = hn[0];
                op[1] = hn[1];
            }
        }

        // ---- stage 6: off-critical-path — stage x(t+1); prefetch own-h ----
        if (t + 1 < TSTEPS && tid < 256) {
            stage_x(t + 1, An);
            const ull* sph = hb_own + (size_t)(t & (RING - 1)) * SLOT_ULL + grow * 128 + g16 * 8;
#pragma unroll
            for (int j = 0; j < 8; ++j)
                vh[j] = __hip_atomic_load(sph + j, __ATOMIC_RELAXED, __HIP_MEMORY_SCOPE_SYSTEM);
        }
        __syncthreads();   // B3: step t fully consumed

        if (tid == 0)
            __hip_atomic_store(my_flag, (unsigned)(t + 1),
                               __ATOMIC_RELAXED, __HIP_MEMORY_SCOPE_SYSTEM);
    }
}

extern "C" void kernel_launch(void* const* d_in, const int* in_sizes, int n_in,
                              void* d_out, int out_size, void* d_ws, size_t ws_size,
                              hipStream_t stream)
{
    const float* x     = (const float*)d_in[0];
    const float* k0    = (const float*)d_in[1];
    const float* rk0   = (const float*)d_in[2];
    const float* b0    = (const float*)d_in[3];
    const float* kern  = (const float*)d_in[4];
    const float* rkern = (const float*)d_in[5];
    const float* bias  = (const float*)d_in[6];
    float* out = (float*)d_out;

    char* ws = (char*)d_ws;
    _Float16*     Wp    = (_Float16*)(ws + WP_OFF);
    float*        Bp    = (float*)(ws + BP_OFF);
    unsigned int* flags = (unsigned int*)(ws + FLAG_OFF);
    ull*          hbuf  = (ull*)(ws + HBUF_OFF);

    hipMemsetAsync(flags, 0, FLAG_BYTES, stream);

    const int total = LAYERS * WPL + LAYERS * 1024;
    repack_kernel<<<(total + 255) / 256, 256, 0, stream>>>(k0, rk0, b0, kern, rkern, bias, Wp, Bp);

    gru_kernel<<<LAYERS * NCH * 8, 384, 0, stream>>>(x, Wp, Bp, hbuf, flags, out);
}